// Round 7
// baseline (444.406 us; speedup 1.0000x reference)
//
#include <hip/hip_runtime.h>
#include <math.h>

// Problem constants
#define E_TOT 1048576
#define NB    64          // graphs
#define HD    128         // hidden dim
#define NN1   65536       // nodes stage1 (64*1024)
#define NN2   32768       // nodes stage2 (64*512)
#define NN3   16384       // nodes stage3 (64*256)
#define CAP   18432       // per-graph edge bin capacity (mean 16384 + 16 sigma)

// ----------------------------------------------------------------------------
// edge_index dtype probe: if the harness kept int64, every odd 32-bit word of
// the first 32 entries is 0 (values < 2^16). Sets *flag = 1 for int64.
__global__ void probe_kernel(const int* __restrict__ ei, int* __restrict__ flag) {
    if (blockIdx.x == 0 && threadIdx.x == 0) {
        int w = 1;
        for (int i = 1; i < 64; i += 2) if (ei[i] != 0) { w = 0; break; }
        *flag = w;
    }
}

// ----------------------------------------------------------------------------
// Stage-1 edge build, phase 1: block-level counting sort by graph id.
__global__ __launch_bounds__(256) void bin_pack_kernel(const int* __restrict__ ei,
                                                       const int* __restrict__ wflag,
                                                       int* __restrict__ bins,
                                                       int* __restrict__ gcur) {
    __shared__ int hist[64];
    __shared__ int base[64];
    __shared__ int gpos[64];
    __shared__ int stage[4096];
    const int t = threadIdx.x;
    const int wide = *wflag;
    const int e0 = blockIdx.x * 4096;

    int pk[16];
    #pragma unroll
    for (int j = 0; j < 16; ++j) {
        int e = e0 + j * 256 + t;
        int s, d;
        if (wide) { s = ei[2 * e]; d = ei[2 * (E_TOT + e)]; }
        else      { s = ei[e];     d = ei[E_TOT + e]; }
        int g = d >> 10;
        pk[j] = (g << 20) | ((d & 1023) << 10) | (s & 1023);
    }
    if (t < 64) hist[t] = 0;
    __syncthreads();
    #pragma unroll
    for (int j = 0; j < 16; ++j) atomicAdd(&hist[pk[j] >> 20], 1);
    __syncthreads();
    if (t < 64) {
        int v = hist[t];
        int inc = v;
        #pragma unroll
        for (int d = 1; d < 64; d <<= 1) { int u = __shfl_up(inc, d); if (t >= d) inc += u; }
        base[t] = inc - v;                       // exclusive within tile
        gpos[t] = atomicAdd(&gcur[t], v);        // reserve global run
    }
    __syncthreads();
    if (t < 64) hist[t] = base[t];               // reuse as cursor
    __syncthreads();
    #pragma unroll
    for (int j = 0; j < 16; ++j) {
        int p = atomicAdd(&hist[pk[j] >> 20], 1);
        stage[p] = pk[j];
    }
    __syncthreads();
    #pragma unroll
    for (int j = 0; j < 16; ++j) {
        int i = j * 256 + t;
        int v = stage[i];
        int g = v >> 20;
        int dst = gpos[g] + (i - base[g]);
        if (dst < CAP) bins[g * CAP + dst] = v;
    }
}

// ----------------------------------------------------------------------------
// Stage-1 edge build, phase 2: one block per graph.
__global__ __launch_bounds__(1024) void graph_csr_kernel(const int* __restrict__ bins,
                                                         const int* __restrict__ gcur,
                                                         int* __restrict__ offs,
                                                         float* __restrict__ rs,
                                                         int* __restrict__ csr) {
    __shared__ int deg[1024];
    __shared__ int cur[1024];
    __shared__ int wsum[16];
    __shared__ int ebase_s;
    const int g = blockIdx.x, t = threadIdx.x;
    const int lane = t & 63, wv = t >> 6;

    if (t < 64) {
        int v = gcur[t];
        int inc = v;
        #pragma unroll
        for (int d = 1; d < 64; d <<= 1) { int u = __shfl_up(inc, d); if (t >= d) inc += u; }
        if (t == g) ebase_s = inc - v;
    }
    deg[t] = 0;
    __syncthreads();
    const int cnt = gcur[g];
    const int ebase = ebase_s;
    const int* bin = bins + g * CAP;

    for (int i = t; i < cnt; i += 1024)
        atomicAdd(&deg[(bin[i] >> 10) & 1023], 1);
    __syncthreads();

    int dv = deg[t];
    int inc = dv;
    #pragma unroll
    for (int d = 1; d < 64; d <<= 1) { int u = __shfl_up(inc, d); if (lane >= d) inc += u; }
    if (lane == 63) wsum[wv] = inc;
    __syncthreads();
    if (t < 16) {
        int v = wsum[t];
        int inc2 = v;
        #pragma unroll
        for (int d = 1; d < 16; d <<= 1) { int u = __shfl_up(inc2, d); if (t >= d) inc2 += u; }
        wsum[t] = inc2 - v;
    }
    __syncthreads();
    int ex = inc - dv + wsum[wv];
    offs[g * 1024 + t] = ebase + ex;
    rs[g * 1024 + t]   = rsqrtf((float)(dv + 1));
    cur[t] = ex;
    if (g == NB - 1 && t == 1023) offs[NN1] = ebase + ex + dv;
    __syncthreads();

    for (int i = t; i < cnt; i += 1024) {
        int v = bin[i];
        int p = atomicAdd(&cur[(v >> 10) & 1023], 1);
        csr[ebase + p] = (g << 10) + (v & 1023);
    }
}

// ----------------------------------------------------------------------------
// CSR-to-CSR pooling build.
__global__ __launch_bounds__(256) void csr_count_kernel(const int* __restrict__ old_offs,
                                                        const int* __restrict__ old_csr,
                                                        const int* __restrict__ map,
                                                        const int* __restrict__ sel,
                                                        int* __restrict__ deg, int nnew) {
    int wid  = (blockIdx.x * blockDim.x + threadIdx.x) >> 6;
    int lane = threadIdx.x & 63;
    if (wid >= nnew) return;
    int old = sel[wid];
    int beg = old_offs[old], end = old_offs[old + 1];
    int cnt = 0;
    for (int base = beg; base < end; base += 64) {
        int i = base + lane;
        int keep = 0;
        if (i < end) keep = (map[old_csr[i]] >= 0);
        cnt += keep;
    }
    #pragma unroll
    for (int d = 32; d; d >>= 1) cnt += __shfl_xor(cnt, d);
    if (lane == 0) deg[wid] = cnt;
}

__global__ __launch_bounds__(256) void csr_scatter_kernel(const int* __restrict__ old_offs,
                                                          const int* __restrict__ old_csr,
                                                          const int* __restrict__ map,
                                                          const int* __restrict__ sel,
                                                          const int* __restrict__ new_offs,
                                                          int* __restrict__ new_csr, int nnew) {
    int wid  = (blockIdx.x * blockDim.x + threadIdx.x) >> 6;
    int lane = threadIdx.x & 63;
    if (wid >= nnew) return;
    int old = sel[wid];
    int beg = old_offs[old], end = old_offs[old + 1];
    int cur = new_offs[wid];
    for (int base = beg; base < end; base += 64) {
        int i = base + lane;
        int ns = -1;
        if (i < end) ns = map[old_csr[i]];
        unsigned long long b = __ballot(ns >= 0);
        int pos = __popcll(b & ((1ULL << lane) - 1));
        if (ns >= 0) new_csr[cur + pos] = ns;
        cur += __popcll(b);
    }
}

// ----------------------------------------------------------------------------
// multi-block exclusive scan over n degrees (n multiple of 1024). (stages 2/3)
__global__ __launch_bounds__(256) void scan_sum_kernel(const int* __restrict__ deg,
                                                       int* __restrict__ bsum) {
    int b = blockIdx.x;
    const int4 v = *(const int4*)(deg + b * 1024 + threadIdx.x * 4);
    int s = v.x + v.y + v.z + v.w;
    #pragma unroll
    for (int d = 32; d; d >>= 1) s += __shfl_xor(s, d);
    __shared__ int wsum[4];
    if ((threadIdx.x & 63) == 0) wsum[threadIdx.x >> 6] = s;
    __syncthreads();
    if (threadIdx.x == 0) bsum[b] = wsum[0] + wsum[1] + wsum[2] + wsum[3];
}

__global__ __launch_bounds__(64) void scan_bsum_kernel(int* __restrict__ bsum, int nb) {
    int t = threadIdx.x;
    int v = (t < nb) ? bsum[t] : 0;
    #pragma unroll
    for (int d = 1; d < 64; d <<= 1) {
        int u = __shfl_up(v, d);
        if (t >= d) v += u;
    }
    int ex = __shfl_up(v, 1);
    if (t == 0) ex = 0;
    if (t < nb) bsum[t] = ex;
}

__global__ __launch_bounds__(256) void scan_out_kernel(const int* __restrict__ deg,
                                                       const int* __restrict__ bsum,
                                                       int* __restrict__ offs,
                                                       int* __restrict__ cursor,
                                                       float* __restrict__ rs, int n) {
    int b = blockIdx.x, t = threadIdx.x;
    int lane = t & 63, wv = t >> 6;
    int idx = b * 1024 + t * 4;
    const int4 v = *(const int4*)(deg + idx);
    int s = v.x + v.y + v.z + v.w;
    int inc = s;
    #pragma unroll
    for (int d = 1; d < 64; d <<= 1) {
        int u = __shfl_up(inc, d);
        if (lane >= d) inc += u;
    }
    __shared__ int wsum[4];
    if (lane == 63) wsum[wv] = inc;
    __syncthreads();
    int woff = 0;
    for (int i = 0; i < wv; ++i) woff += wsum[i];
    int ex = inc - s + woff + bsum[b];
    int4 o; o.x = ex; o.y = o.x + v.x; o.z = o.y + v.y; o.w = o.z + v.z;
    *(int4*)(offs + idx)   = o;
    *(int4*)(cursor + idx) = o;
    float4 r;
    r.x = rsqrtf((float)(v.x + 1)); r.y = rsqrtf((float)(v.y + 1));
    r.z = rsqrtf((float)(v.z + 1)); r.w = rsqrtf((float)(v.w + 1));
    *(float4*)(rs + idx) = r;
    if (idx + 4 == n) offs[n] = o.w + v.w;
}

// ----------------------------------------------------------------------------
// Tiled f32 GEMM: Y[M,128] = X[M,128] @ W[128,128].
__global__ __launch_bounds__(256) void gemm_tiled_kernel(const float* __restrict__ X,
                                                         const float* __restrict__ W,
                                                         float* __restrict__ Y) {
    __shared__ float sXT[8][128];
    __shared__ float sW[8][128];
    const int t = threadIdx.x;
    const long long row0 = (long long)blockIdx.x * 128;
    const int r0 = (t >> 4) << 3;
    const int c0 = (t & 15) << 3;
    const int lm  = t >> 1;
    const int lk  = (t & 1) << 2;
    const int wk  = t >> 5;
    const int wc4 = (t & 31) << 2;

    float acc[8][8];
    #pragma unroll
    for (int i = 0; i < 8; ++i)
        #pragma unroll
        for (int j = 0; j < 8; ++j) acc[i][j] = 0.f;

    for (int k0 = 0; k0 < 128; k0 += 8) {
        __syncthreads();
        float4 xv = *(const float4*)(X + (row0 + lm) * 128 + k0 + lk);
        float4 wv = *(const float4*)(W + (k0 + wk) * 128 + wc4);
        sXT[lk + 0][lm] = xv.x;
        sXT[lk + 1][lm] = xv.y;
        sXT[lk + 2][lm] = xv.z;
        sXT[lk + 3][lm] = xv.w;
        *(float4*)&sW[wk][wc4] = wv;
        __syncthreads();
        #pragma unroll
        for (int kk = 0; kk < 8; ++kk) {
            float4 xa = *(const float4*)&sXT[kk][r0];
            float4 xb = *(const float4*)&sXT[kk][r0 + 4];
            float4 wa = *(const float4*)&sW[kk][c0];
            float4 wb = *(const float4*)&sW[kk][c0 + 4];
            float xr[8]  = {xa.x, xa.y, xa.z, xa.w, xb.x, xb.y, xb.z, xb.w};
            float wcv[8] = {wa.x, wa.y, wa.z, wa.w, wb.x, wb.y, wb.z, wb.w};
            #pragma unroll
            for (int i = 0; i < 8; ++i)
                #pragma unroll
                for (int j = 0; j < 8; ++j)
                    acc[i][j] = fmaf(xr[i], wcv[j], acc[i][j]);
        }
    }

    #pragma unroll
    for (int i = 0; i < 8; ++i) {
        float* yp = Y + (row0 + r0 + i) * 128 + c0;
        float4 o0; o0.x = acc[i][0]; o0.y = acc[i][1]; o0.z = acc[i][2]; o0.w = acc[i][3];
        float4 o1; o1.x = acc[i][4]; o1.y = acc[i][5]; o1.z = acc[i][6]; o1.w = acc[i][7];
        *(float4*)yp       = o0;
        *(float4*)(yp + 4) = o1;
    }
}

// ----------------------------------------------------------------------------
// GCN aggregation: one wave per dst node, float2 per lane (128 dims).
// XCD-aware swizzle: blocks of graph g land on XCD g%8 (blockIdx%8 -> XCD),
// so each XCD's gather working set = 8 graphs = exactly its 4MB L2.
// npg = nodes per graph; lbshift = log2(npg/4) (blocks per graph).
__global__ __launch_bounds__(256) void agg_kernel(const float* __restrict__ h,
                                                  const int* __restrict__ csr,
                                                  const int* __restrict__ offs,
                                                  const float* __restrict__ rs,
                                                  const float* __restrict__ bias,
                                                  const float* __restrict__ ws,
                                                  float* __restrict__ hrelu,
                                                  float* __restrict__ score,
                                                  int npg, int lbshift) {
    const int lane = threadIdx.x & 63;
    const int wvb  = threadIdx.x >> 6;
    int b   = blockIdx.x;
    int xcd = b & 7;
    int i   = b >> 3;
    int gi  = i >> lbshift;
    int lb  = i & ((1 << lbshift) - 1);
    int g   = xcd + (gi << 3);
    int v   = g * npg + (lb << 2) + wvb;

    int beg = offs[v], end = offs[v + 1];
    float rv = rs[v];
    const float2* h2 = (const float2*)h;
    float ax = 0.f, ay = 0.f;
    for (int base = beg; base < end; base += 64) {
        int idx = base + lane;
        int sv = (idx < end) ? csr[idx] : 0;
        int m = end - base; if (m > 64) m = 64;
        int j = 0;
        for (; j + 4 <= m; j += 4) {
            int s0 = __shfl(sv, j);
            int s1 = __shfl(sv, j + 1);
            int s2 = __shfl(sv, j + 2);
            int s3 = __shfl(sv, j + 3);
            float n0 = rs[s0] * rv, n1 = rs[s1] * rv, n2 = rs[s2] * rv, n3 = rs[s3] * rv;
            float2 h0 = h2[(long long)s0 * 64 + lane];
            float2 h1 = h2[(long long)s1 * 64 + lane];
            float2 hv2 = h2[(long long)s2 * 64 + lane];
            float2 h3 = h2[(long long)s3 * 64 + lane];
            ax = fmaf(h0.x, n0, ax); ay = fmaf(h0.y, n0, ay);
            ax = fmaf(h1.x, n1, ax); ay = fmaf(h1.y, n1, ay);
            ax = fmaf(hv2.x, n2, ax); ay = fmaf(hv2.y, n2, ay);
            ax = fmaf(h3.x, n3, ax); ay = fmaf(h3.y, n3, ay);
        }
        for (; j < m; ++j) {
            int s = __shfl(sv, j);
            float nrm = rs[s] * rv;
            float2 hv = h2[(long long)s * 64 + lane];
            ax = fmaf(hv.x, nrm, ax); ay = fmaf(hv.y, nrm, ay);
        }
    }
    float2 hv = h2[(long long)v * 64 + lane];
    float inv = rv * rv;
    float ox = ax + hv.x * inv + bias[2 * lane];
    float oy = ay + hv.y * inv + bias[2 * lane + 1];
    float p = ox * ws[2 * lane] + oy * ws[2 * lane + 1];
    #pragma unroll
    for (int d = 32; d; d >>= 1) p += __shfl_xor(p, d);
    if (lane == 0) score[v] = p;
    float2 o; o.x = fmaxf(ox, 0.f); o.y = fmaxf(oy, 0.f);
    ((float2*)hrelu)[(long long)v * 64 + lane] = o;
}

// ----------------------------------------------------------------------------
// per-graph top-k via bitonic sort (descending). n<=1024.
__global__ __launch_bounds__(512) void topk_kernel(const float* __restrict__ score,
                                                   int* __restrict__ newpos,
                                                   int* __restrict__ sel,
                                                   float* __restrict__ scale,
                                                   int n, int k) {
    __shared__ float key[1024];
    __shared__ int   kid[1024];
    int g = blockIdx.x;
    for (int i = threadIdx.x; i < n; i += blockDim.x) {
        key[i] = score[g * n + i];
        kid[i] = i;
    }
    __syncthreads();
    for (int kk = 2; kk <= n; kk <<= 1) {
        for (int j = kk >> 1; j > 0; j >>= 1) {
            for (int i = threadIdx.x; i < n; i += blockDim.x) {
                int ixj = i ^ j;
                if (ixj > i) {
                    bool dir = ((i & kk) == 0);
                    float a = key[i], b = key[ixj];
                    if ((a < b) == dir) {
                        key[i] = b; key[ixj] = a;
                        int tmp = kid[i]; kid[i] = kid[ixj]; kid[ixj] = tmp;
                    }
                }
            }
            __syncthreads();
        }
    }
    for (int i = threadIdx.x; i < n; i += blockDim.x) {
        int old = g * n + kid[i];
        if (i < k) {
            int nid = g * k + i;
            newpos[old] = nid;
            sel[nid]    = old;
            scale[nid]  = tanhf(key[i]);
        } else {
            newpos[old] = -1;
        }
    }
}

// ----------------------------------------------------------------------------
// pooled[new] = hrelu[sel[new]] * scale[new]   (one wave per new node)
__global__ __launch_bounds__(256) void pool_gather_kernel(const float* __restrict__ hrelu,
                                                          const int* __restrict__ sel,
                                                          const float* __restrict__ scale,
                                                          float* __restrict__ pooled, int nnew) {
    int wid  = (blockIdx.x * blockDim.x + threadIdx.x) >> 6;
    int lane = threadIdx.x & 63;
    if (wid >= nnew) return;
    int old  = sel[wid];
    float sc = scale[wid];
    float2 v = ((const float2*)hrelu)[(long long)old * 64 + lane];
    float2 o; o.x = v.x * sc; o.y = v.y * sc;
    ((float2*)pooled)[(long long)wid * 64 + lane] = o;
}

// ----------------------------------------------------------------------------
// two-phase readout.
__global__ __launch_bounds__(128) void readout_part_kernel(const float* __restrict__ h,
                                                           float* __restrict__ part, int npg) {
    int b = blockIdx.x;
    int g = b >> 3, c = b & 7;
    int f = threadIdx.x;
    int chunk = npg >> 3;
    const float* base = h + ((long long)g * npg + (long long)c * chunk) * 128;
    float m = -INFINITY, s = 0.f;
    for (int n = 0; n < chunk; ++n) {
        float v = base[n * 128 + f];
        m = fmaxf(m, v);
        s += v;
    }
    part[(size_t)b * 256 + f]       = m;
    part[(size_t)b * 256 + 128 + f] = s;
}

__global__ __launch_bounds__(128) void readout_fin_kernel(const float* __restrict__ part,
                                                          float* __restrict__ xout, int npg) {
    int g = blockIdx.x, f = threadIdx.x;
    float m = -INFINITY, s = 0.f;
    #pragma unroll
    for (int c = 0; c < 8; ++c) {
        m = fmaxf(m, part[(size_t)(g * 8 + c) * 256 + f]);
        s += part[(size_t)(g * 8 + c) * 256 + 128 + f];
    }
    xout[g * 256 + f]       = m;
    xout[g * 256 + 128 + f] = s / (float)npg;
}

// ----------------------------------------------------------------------------
// final MLP head + log_softmax. block=(128), grid=(64)
__global__ __launch_bounds__(128) void mlp_kernel(const float* __restrict__ x1,
                                                  const float* __restrict__ x2,
                                                  const float* __restrict__ x3,
                                                  const float* __restrict__ L1w,
                                                  const float* __restrict__ L1b,
                                                  const float* __restrict__ L2w,
                                                  const float* __restrict__ L2b,
                                                  const float* __restrict__ L3w,
                                                  const float* __restrict__ L3b,
                                                  float* __restrict__ out) {
    __shared__ float z[256], z1[128], z2[64], z3[6];
    int g = blockIdx.x, t = threadIdx.x;
    z[t]       = fmaxf(x1[g * 256 + t], 0.f) + fmaxf(x2[g * 256 + t], 0.f) +
                 fmaxf(x3[g * 256 + t], 0.f);
    z[t + 128] = fmaxf(x1[g * 256 + 128 + t], 0.f) + fmaxf(x2[g * 256 + 128 + t], 0.f) +
                 fmaxf(x3[g * 256 + 128 + t], 0.f);
    __syncthreads();
    float a = L1b[t];
    for (int i = 0; i < 256; ++i) a += z[i] * L1w[i * 128 + t];
    z1[t] = fmaxf(a, 0.f);
    __syncthreads();
    if (t < 64) {
        float b = L2b[t];
        for (int i = 0; i < 128; ++i) b += z1[i] * L2w[i * 64 + t];
        z2[t] = fmaxf(b, 0.f);
    }
    __syncthreads();
    if (t < 6) {
        float c = L3b[t];
        for (int i = 0; i < 64; ++i) c += z2[i] * L3w[i * 6 + t];
        z3[t] = c;
    }
    __syncthreads();
    if (t == 0) {
        float m = z3[0];
        for (int i = 1; i < 6; ++i) m = fmaxf(m, z3[i]);
        float s = 0.f;
        for (int i = 0; i < 6; ++i) s += expf(z3[i] - m);
        float ls = m + logf(s);
        for (int i = 0; i < 6; ++i) out[g * 6 + i] = z3[i] - ls;
    }
}

// ----------------------------------------------------------------------------
static inline void run_scan(const int* deg, int* bsum, int* offs, int* cur, float* rs,
                            int n, hipStream_t stream) {
    int nb = n / 1024;
    scan_sum_kernel<<<nb, 256, 0, stream>>>(deg, bsum);
    scan_bsum_kernel<<<1, 64, 0, stream>>>(bsum, nb);
    scan_out_kernel<<<nb, 256, 0, stream>>>(deg, bsum, offs, cur, rs, n);
}

static inline void run_readout(const float* h, float* part, float* xout, int npg,
                               hipStream_t stream) {
    readout_part_kernel<<<NB * 8, 128, 0, stream>>>(h, part, npg);
    readout_fin_kernel<<<NB, 128, 0, stream>>>(part, xout, npg);
}

extern "C" void kernel_launch(void* const* d_in, const int* in_sizes, int n_in,
                              void* d_out, int out_size, void* d_ws, size_t ws_size,
                              hipStream_t stream) {
    const float* x    = (const float*)d_in[0];
    const int*   ei   = (const int*)d_in[1];
    const float* W1   = (const float*)d_in[3];
    const float* b1   = (const float*)d_in[4];
    const float* ws1  = (const float*)d_in[5];
    const float* W2   = (const float*)d_in[6];
    const float* b2   = (const float*)d_in[7];
    const float* ws2  = (const float*)d_in[8];
    const float* W3   = (const float*)d_in[9];
    const float* b3   = (const float*)d_in[10];
    const float* ws3  = (const float*)d_in[11];
    const float* L1w  = (const float*)d_in[12];
    const float* L1b  = (const float*)d_in[13];
    const float* L2w  = (const float*)d_in[14];
    const float* L2b  = (const float*)d_in[15];
    const float* L3w  = (const float*)d_in[16];
    const float* L3b  = (const float*)d_in[17];
    float* out = (float*)d_out;

    // workspace layout (256B aligned regions)
    char* w = (char*)d_ws;
    auto alloc = [&](size_t nbytes) { char* p = w; w += (nbytes + 255) & ~(size_t)255; return p; };
    float* A     = (float*)alloc((size_t)NN1 * 128 * 4);   // h = X @ W
    float* Bf    = (float*)alloc((size_t)NN1 * 128 * 4);   // relu(out); tail hosts csrB
    float* P1    = (float*)alloc((size_t)NN2 * 128 * 4);   // pooled stage1
    float* P2    = (float*)alloc((size_t)NN3 * 128 * 4);   // pooled stage2 / bins union
    int*   csrA  = (int*)alloc((size_t)E_TOT * 4);
    int*   deg   = (int*)alloc((size_t)NN1 * 4);
    int*   offsA = (int*)alloc((size_t)(NN1 + 1) * 4);
    int*   offsB = (int*)alloc((size_t)(NN1 + 1) * 4);
    int*   cur   = (int*)alloc((size_t)NN1 * 4);
    float* rs    = (float*)alloc((size_t)NN1 * 4);
    int*   np1   = (int*)alloc((size_t)NN1 * 4);
    int*   np2   = (int*)alloc((size_t)NN2 * 4);
    int*   sel   = (int*)alloc((size_t)NN2 * 4);
    float* scal  = (float*)alloc((size_t)NN2 * 4);
    float* score = (float*)alloc((size_t)NN1 * 4);
    float* x1    = (float*)alloc((size_t)NB * 256 * 4);
    float* x2    = (float*)alloc((size_t)NB * 256 * 4);
    float* x3    = (float*)alloc((size_t)NB * 256 * 4);
    float* part  = (float*)alloc((size_t)NB * 8 * 256 * 4);
    int*   bsum  = (int*)alloc(256 * 4);
    int*   gcur  = (int*)alloc(64 * 4);
    int*   flag  = (int*)alloc(256);

    // overlays (regions dead at time of use)
    int* bins = (int*)P2;                       // 64*CAP*4 = 4.7MB < NN3*128*4; dead before stage-2 pool
    int* csrB = (int*)(Bf + (size_t)NN2 * 128); // Bf tail unused after stage-1 pool

    probe_kernel<<<1, 64, 0, stream>>>(ei, flag);

    // ---------------- stage 1 (two-level counting-sort CSR build) ----------------
    hipMemsetAsync(gcur, 0, 64 * 4, stream);
    bin_pack_kernel<<<E_TOT / 4096, 256, 0, stream>>>(ei, flag, bins, gcur);
    graph_csr_kernel<<<NB, 1024, 0, stream>>>(bins, gcur, offsA, rs, csrA);
    gemm_tiled_kernel<<<NN1 / 128, 256, 0, stream>>>(x, W1, A);
    agg_kernel<<<NN1 / 4, 256, 0, stream>>>(A, csrA, offsA, rs, b1, ws1, Bf, score, 1024, 8);
    topk_kernel<<<NB, 512, 0, stream>>>(score, np1, sel, scal, 1024, 512);
    pool_gather_kernel<<<NN2 / 4, 256, 0, stream>>>(Bf, sel, scal, P1, NN2);
    run_readout(P1, part, x1, 512, stream);

    // ---------------- stage 2 (CSR from stage-1 CSR) ----------------
    csr_count_kernel<<<NN2 / 4, 256, 0, stream>>>(offsA, csrA, np1, sel, deg, NN2);
    run_scan(deg, bsum, offsB, cur, rs, NN2, stream);
    csr_scatter_kernel<<<NN2 / 4, 256, 0, stream>>>(offsA, csrA, np1, sel, offsB, csrB, NN2);
    gemm_tiled_kernel<<<NN2 / 128, 256, 0, stream>>>(P1, W2, A);
    agg_kernel<<<NN2 / 4, 256, 0, stream>>>(A, csrB, offsB, rs, b2, ws2, Bf, score, 512, 7);
    topk_kernel<<<NB, 512, 0, stream>>>(score, np2, sel, scal, 512, 256);
    pool_gather_kernel<<<NN3 / 4, 256, 0, stream>>>(Bf, sel, scal, P2, NN3);
    run_readout(P2, part, x2, 256, stream);

    // ---------------- stage 3 (CSR from stage-2 CSR) ----------------
    csr_count_kernel<<<NN3 / 4, 256, 0, stream>>>(offsB, csrB, np2, sel, deg, NN3);
    run_scan(deg, bsum, offsA, cur, rs, NN3, stream);
    csr_scatter_kernel<<<NN3 / 4, 256, 0, stream>>>(offsB, csrB, np2, sel, offsA, csrA, NN3);
    gemm_tiled_kernel<<<NN3 / 128, 256, 0, stream>>>(P2, W3, A);
    agg_kernel<<<NN3 / 4, 256, 0, stream>>>(A, csrA, offsA, rs, b3, ws3, Bf, score, 256, 6);
    run_readout(Bf, part, x3, 256, stream);

    // ---------------- head ----------------
    mlp_kernel<<<NB, 128, 0, stream>>>(x1, x2, x3, L1w, L1b, L2w, L2b, L3w, L3b, out);
}

// Round 9
// 437.104 us; speedup vs baseline: 1.0167x; 1.0167x over previous
//
#include <hip/hip_runtime.h>
#include <math.h>

// Problem constants
#define E_TOT 1048576
#define NB    64          // graphs
#define HD    128         // hidden dim
#define NN1   65536       // nodes stage1 (64*1024)
#define NN2   32768       // nodes stage2 (64*512)
#define NN3   16384       // nodes stage3 (64*256)
#define CAP   18432       // per-graph edge bin capacity (mean 16384 + 16 sigma)

// ----------------------------------------------------------------------------
// edge_index dtype probe: if the harness kept int64, every odd 32-bit word of
// the first 32 entries is 0 (values < 2^16). Sets *flag = 1 for int64.
__global__ void probe_kernel(const int* __restrict__ ei, int* __restrict__ flag) {
    if (blockIdx.x == 0 && threadIdx.x == 0) {
        int w = 1;
        for (int i = 1; i < 64; i += 2) if (ei[i] != 0) { w = 0; break; }
        *flag = w;
    }
}

// ----------------------------------------------------------------------------
// Stage-1 edge build, phase 1: block-level counting sort by graph id.
__global__ __launch_bounds__(256) void bin_pack_kernel(const int* __restrict__ ei,
                                                       const int* __restrict__ wflag,
                                                       int* __restrict__ bins,
                                                       int* __restrict__ gcur) {
    __shared__ int hist[64];
    __shared__ int base[64];
    __shared__ int gpos[64];
    __shared__ int stage[4096];
    const int t = threadIdx.x;
    const int wide = *wflag;
    const int e0 = blockIdx.x * 4096;

    int pk[16];
    #pragma unroll
    for (int j = 0; j < 16; ++j) {
        int e = e0 + j * 256 + t;
        int s, d;
        if (wide) { s = ei[2 * e]; d = ei[2 * (E_TOT + e)]; }
        else      { s = ei[e];     d = ei[E_TOT + e]; }
        int g = d >> 10;
        pk[j] = (g << 20) | ((d & 1023) << 10) | (s & 1023);
    }
    if (t < 64) hist[t] = 0;
    __syncthreads();
    #pragma unroll
    for (int j = 0; j < 16; ++j) atomicAdd(&hist[pk[j] >> 20], 1);
    __syncthreads();
    if (t < 64) {
        int v = hist[t];
        int inc = v;
        #pragma unroll
        for (int d = 1; d < 64; d <<= 1) { int u = __shfl_up(inc, d); if (t >= d) inc += u; }
        base[t] = inc - v;                       // exclusive within tile
        gpos[t] = atomicAdd(&gcur[t], v);        // reserve global run
    }
    __syncthreads();
    if (t < 64) hist[t] = base[t];               // reuse as cursor
    __syncthreads();
    #pragma unroll
    for (int j = 0; j < 16; ++j) {
        int p = atomicAdd(&hist[pk[j] >> 20], 1);
        stage[p] = pk[j];
    }
    __syncthreads();
    #pragma unroll
    for (int j = 0; j < 16; ++j) {
        int i = j * 256 + t;
        int v = stage[i];
        int g = v >> 20;
        int dst = gpos[g] + (i - base[g]);
        if (dst < CAP) bins[g * CAP + dst] = v;
    }
}

// ----------------------------------------------------------------------------
// Stage-1 edge build, phase 2: one block per graph.
__global__ __launch_bounds__(1024) void graph_csr_kernel(const int* __restrict__ bins,
                                                         const int* __restrict__ gcur,
                                                         int* __restrict__ offs,
                                                         float* __restrict__ rs,
                                                         int* __restrict__ csr) {
    __shared__ int deg[1024];
    __shared__ int cur[1024];
    __shared__ int wsum[16];
    __shared__ int ebase_s;
    const int g = blockIdx.x, t = threadIdx.x;
    const int lane = t & 63, wv = t >> 6;

    if (t < 64) {
        int v = gcur[t];
        int inc = v;
        #pragma unroll
        for (int d = 1; d < 64; d <<= 1) { int u = __shfl_up(inc, d); if (t >= d) inc += u; }
        if (t == g) ebase_s = inc - v;
    }
    deg[t] = 0;
    __syncthreads();
    const int cnt = gcur[g];
    const int ebase = ebase_s;
    const int* bin = bins + g * CAP;

    for (int i = t; i < cnt; i += 1024)
        atomicAdd(&deg[(bin[i] >> 10) & 1023], 1);
    __syncthreads();

    int dv = deg[t];
    int inc = dv;
    #pragma unroll
    for (int d = 1; d < 64; d <<= 1) { int u = __shfl_up(inc, d); if (lane >= d) inc += u; }
    if (lane == 63) wsum[wv] = inc;
    __syncthreads();
    if (t < 16) {
        int v = wsum[t];
        int inc2 = v;
        #pragma unroll
        for (int d = 1; d < 16; d <<= 1) { int u = __shfl_up(inc2, d); if (t >= d) inc2 += u; }
        wsum[t] = inc2 - v;
    }
    __syncthreads();
    int ex = inc - dv + wsum[wv];
    offs[g * 1024 + t] = ebase + ex;
    rs[g * 1024 + t]   = rsqrtf((float)(dv + 1));
    cur[t] = ex;
    if (g == NB - 1 && t == 1023) offs[NN1] = ebase + ex + dv;
    __syncthreads();

    for (int i = t; i < cnt; i += 1024) {
        int v = bin[i];
        int p = atomicAdd(&cur[(v >> 10) & 1023], 1);
        csr[ebase + p] = (g << 10) + (v & 1023);
    }
}

// ----------------------------------------------------------------------------
// CSR-to-CSR pooling build.
__global__ __launch_bounds__(256) void csr_count_kernel(const int* __restrict__ old_offs,
                                                        const int* __restrict__ old_csr,
                                                        const int* __restrict__ map,
                                                        const int* __restrict__ sel,
                                                        int* __restrict__ deg, int nnew) {
    int wid  = (blockIdx.x * blockDim.x + threadIdx.x) >> 6;
    int lane = threadIdx.x & 63;
    if (wid >= nnew) return;
    int old = sel[wid];
    int beg = old_offs[old], end = old_offs[old + 1];
    int cnt = 0;
    for (int base = beg; base < end; base += 64) {
        int i = base + lane;
        int keep = 0;
        if (i < end) keep = (map[old_csr[i]] >= 0);
        cnt += keep;
    }
    #pragma unroll
    for (int d = 32; d; d >>= 1) cnt += __shfl_xor(cnt, d);
    if (lane == 0) deg[wid] = cnt;
}

__global__ __launch_bounds__(256) void csr_scatter_kernel(const int* __restrict__ old_offs,
                                                          const int* __restrict__ old_csr,
                                                          const int* __restrict__ map,
                                                          const int* __restrict__ sel,
                                                          const int* __restrict__ new_offs,
                                                          int* __restrict__ new_csr, int nnew) {
    int wid  = (blockIdx.x * blockDim.x + threadIdx.x) >> 6;
    int lane = threadIdx.x & 63;
    if (wid >= nnew) return;
    int old = sel[wid];
    int beg = old_offs[old], end = old_offs[old + 1];
    int cur = new_offs[wid];
    for (int base = beg; base < end; base += 64) {
        int i = base + lane;
        int ns = -1;
        if (i < end) ns = map[old_csr[i]];
        unsigned long long b = __ballot(ns >= 0);
        int pos = __popcll(b & ((1ULL << lane) - 1));
        if (ns >= 0) new_csr[cur + pos] = ns;
        cur += __popcll(b);
    }
}

// ----------------------------------------------------------------------------
// multi-block exclusive scan over n degrees (n multiple of 1024). (stages 2/3)
__global__ __launch_bounds__(256) void scan_sum_kernel(const int* __restrict__ deg,
                                                       int* __restrict__ bsum) {
    int b = blockIdx.x;
    const int4 v = *(const int4*)(deg + b * 1024 + threadIdx.x * 4);
    int s = v.x + v.y + v.z + v.w;
    #pragma unroll
    for (int d = 32; d; d >>= 1) s += __shfl_xor(s, d);
    __shared__ int wsum[4];
    if ((threadIdx.x & 63) == 0) wsum[threadIdx.x >> 6] = s;
    __syncthreads();
    if (threadIdx.x == 0) bsum[b] = wsum[0] + wsum[1] + wsum[2] + wsum[3];
}

__global__ __launch_bounds__(64) void scan_bsum_kernel(int* __restrict__ bsum, int nb) {
    int t = threadIdx.x;
    int v = (t < nb) ? bsum[t] : 0;
    #pragma unroll
    for (int d = 1; d < 64; d <<= 1) {
        int u = __shfl_up(v, d);
        if (t >= d) v += u;
    }
    int ex = __shfl_up(v, 1);
    if (t == 0) ex = 0;
    if (t < nb) bsum[t] = ex;
}

__global__ __launch_bounds__(256) void scan_out_kernel(const int* __restrict__ deg,
                                                       const int* __restrict__ bsum,
                                                       int* __restrict__ offs,
                                                       int* __restrict__ cursor,
                                                       float* __restrict__ rs, int n) {
    int b = blockIdx.x, t = threadIdx.x;
    int lane = t & 63, wv = t >> 6;
    int idx = b * 1024 + t * 4;
    const int4 v = *(const int4*)(deg + idx);
    int s = v.x + v.y + v.z + v.w;
    int inc = s;
    #pragma unroll
    for (int d = 1; d < 64; d <<= 1) {
        int u = __shfl_up(inc, d);
        if (lane >= d) inc += u;
    }
    __shared__ int wsum[4];
    if (lane == 63) wsum[wv] = inc;
    __syncthreads();
    int woff = 0;
    for (int i = 0; i < wv; ++i) woff += wsum[i];
    int ex = inc - s + woff + bsum[b];
    int4 o; o.x = ex; o.y = o.x + v.x; o.z = o.y + v.y; o.w = o.z + v.z;
    *(int4*)(offs + idx)   = o;
    *(int4*)(cursor + idx) = o;
    float4 r;
    r.x = rsqrtf((float)(v.x + 1)); r.y = rsqrtf((float)(v.y + 1));
    r.z = rsqrtf((float)(v.z + 1)); r.w = rsqrtf((float)(v.w + 1));
    *(float4*)(rs + idx) = r;
    if (idx + 4 == n) offs[n] = o.w + v.w;
}

// ----------------------------------------------------------------------------
// Tiled f32 GEMM: Y[M,128] = X[M,128] @ W[128,128].
__global__ __launch_bounds__(256) void gemm_tiled_kernel(const float* __restrict__ X,
                                                         const float* __restrict__ W,
                                                         float* __restrict__ Y) {
    __shared__ float sXT[8][128];
    __shared__ float sW[8][128];
    const int t = threadIdx.x;
    const long long row0 = (long long)blockIdx.x * 128;
    const int r0 = (t >> 4) << 3;
    const int c0 = (t & 15) << 3;
    const int lm  = t >> 1;
    const int lk  = (t & 1) << 2;
    const int wk  = t >> 5;
    const int wc4 = (t & 31) << 2;

    float acc[8][8];
    #pragma unroll
    for (int i = 0; i < 8; ++i)
        #pragma unroll
        for (int j = 0; j < 8; ++j) acc[i][j] = 0.f;

    for (int k0 = 0; k0 < 128; k0 += 8) {
        __syncthreads();
        float4 xv = *(const float4*)(X + (row0 + lm) * 128 + k0 + lk);
        float4 wv = *(const float4*)(W + (k0 + wk) * 128 + wc4);
        sXT[lk + 0][lm] = xv.x;
        sXT[lk + 1][lm] = xv.y;
        sXT[lk + 2][lm] = xv.z;
        sXT[lk + 3][lm] = xv.w;
        *(float4*)&sW[wk][wc4] = wv;
        __syncthreads();
        #pragma unroll
        for (int kk = 0; kk < 8; ++kk) {
            float4 xa = *(const float4*)&sXT[kk][r0];
            float4 xb = *(const float4*)&sXT[kk][r0 + 4];
            float4 wa = *(const float4*)&sW[kk][c0];
            float4 wb = *(const float4*)&sW[kk][c0 + 4];
            float xr[8]  = {xa.x, xa.y, xa.z, xa.w, xb.x, xb.y, xb.z, xb.w};
            float wcv[8] = {wa.x, wa.y, wa.z, wa.w, wb.x, wb.y, wb.z, wb.w};
            #pragma unroll
            for (int i = 0; i < 8; ++i)
                #pragma unroll
                for (int j = 0; j < 8; ++j)
                    acc[i][j] = fmaf(xr[i], wcv[j], acc[i][j]);
        }
    }

    #pragma unroll
    for (int i = 0; i < 8; ++i) {
        float* yp = Y + (row0 + r0 + i) * 128 + c0;
        float4 o0; o0.x = acc[i][0]; o0.y = acc[i][1]; o0.z = acc[i][2]; o0.w = acc[i][3];
        float4 o1; o1.x = acc[i][4]; o1.y = acc[i][5]; o1.z = acc[i][6]; o1.w = acc[i][7];
        *(float4*)yp       = o0;
        *(float4*)(yp + 4) = o1;
    }
}

// ----------------------------------------------------------------------------
// GCN aggregation: one wave per dst node, float2 per lane (128 dims).
// SEQUENTIAL edge order (fmaf chain h0..h7 in order) — numerically identical
// to the 4-unroll passing kernel; reassociation flips top-k near-ties (R8
// failure). Unroll x8 -> 8 independent row gathers in flight (latency-bound
// fix). XCD swizzle: blocks of graph g -> XCD g%8 (L2 locality).
__global__ __launch_bounds__(256) void agg_kernel(const float* __restrict__ h,
                                                  const int* __restrict__ csr,
                                                  const int* __restrict__ offs,
                                                  const float* __restrict__ rs,
                                                  const float* __restrict__ bias,
                                                  const float* __restrict__ ws,
                                                  float* __restrict__ hrelu,
                                                  float* __restrict__ score,
                                                  int npg, int lbshift) {
    const int lane = threadIdx.x & 63;
    const int wvb  = threadIdx.x >> 6;
    int b   = blockIdx.x;
    int xcd = b & 7;
    int i   = b >> 3;
    int gi  = i >> lbshift;
    int lb  = i & ((1 << lbshift) - 1);
    int g   = xcd + (gi << 3);
    int v   = g * npg + (lb << 2) + wvb;

    int beg = offs[v], end = offs[v + 1];
    float rv = rs[v];
    const float2* h2 = (const float2*)h;
    float ax = 0.f, ay = 0.f;
    for (int base = beg; base < end; base += 64) {
        int idx = base + lane;
        int sv = (idx < end) ? csr[idx] : 0;
        int m = end - base; if (m > 64) m = 64;
        int j = 0;
        for (; j + 8 <= m; j += 8) {
            int s0 = __shfl(sv, j);
            int s1 = __shfl(sv, j + 1);
            int s2 = __shfl(sv, j + 2);
            int s3 = __shfl(sv, j + 3);
            int s4 = __shfl(sv, j + 4);
            int s5 = __shfl(sv, j + 5);
            int s6 = __shfl(sv, j + 6);
            int s7 = __shfl(sv, j + 7);
            float n0 = rs[s0] * rv, n1 = rs[s1] * rv, n2 = rs[s2] * rv, n3 = rs[s3] * rv;
            float n4 = rs[s4] * rv, n5 = rs[s5] * rv, n6 = rs[s6] * rv, n7 = rs[s7] * rv;
            float2 h0 = h2[(long long)s0 * 64 + lane];
            float2 h1 = h2[(long long)s1 * 64 + lane];
            float2 hq2 = h2[(long long)s2 * 64 + lane];
            float2 h3 = h2[(long long)s3 * 64 + lane];
            float2 h4 = h2[(long long)s4 * 64 + lane];
            float2 h5 = h2[(long long)s5 * 64 + lane];
            float2 h6 = h2[(long long)s6 * 64 + lane];
            float2 h7 = h2[(long long)s7 * 64 + lane];
            ax = fmaf(h0.x, n0, ax); ay = fmaf(h0.y, n0, ay);
            ax = fmaf(h1.x, n1, ax); ay = fmaf(h1.y, n1, ay);
            ax = fmaf(hq2.x, n2, ax); ay = fmaf(hq2.y, n2, ay);
            ax = fmaf(h3.x, n3, ax); ay = fmaf(h3.y, n3, ay);
            ax = fmaf(h4.x, n4, ax); ay = fmaf(h4.y, n4, ay);
            ax = fmaf(h5.x, n5, ax); ay = fmaf(h5.y, n5, ay);
            ax = fmaf(h6.x, n6, ax); ay = fmaf(h6.y, n6, ay);
            ax = fmaf(h7.x, n7, ax); ay = fmaf(h7.y, n7, ay);
        }
        for (; j < m; ++j) {
            int s = __shfl(sv, j);
            float nrm = rs[s] * rv;
            float2 hv = h2[(long long)s * 64 + lane];
            ax = fmaf(hv.x, nrm, ax); ay = fmaf(hv.y, nrm, ay);
        }
    }
    float2 hv = h2[(long long)v * 64 + lane];
    float inv = rv * rv;
    float ox = ax + hv.x * inv + bias[2 * lane];
    float oy = ay + hv.y * inv + bias[2 * lane + 1];
    float p = ox * ws[2 * lane] + oy * ws[2 * lane + 1];
    #pragma unroll
    for (int d = 32; d; d >>= 1) p += __shfl_xor(p, d);
    if (lane == 0) score[v] = p;
    float2 o; o.x = fmaxf(ox, 0.f); o.y = fmaxf(oy, 0.f);
    ((float2*)hrelu)[(long long)v * 64 + lane] = o;
}

// ----------------------------------------------------------------------------
// per-graph top-k via bitonic sort (descending). n<=1024.
__global__ __launch_bounds__(512) void topk_kernel(const float* __restrict__ score,
                                                   int* __restrict__ newpos,
                                                   int* __restrict__ sel,
                                                   float* __restrict__ scale,
                                                   int n, int k) {
    __shared__ float key[1024];
    __shared__ int   kid[1024];
    int g = blockIdx.x;
    for (int i = threadIdx.x; i < n; i += blockDim.x) {
        key[i] = score[g * n + i];
        kid[i] = i;
    }
    __syncthreads();
    for (int kk = 2; kk <= n; kk <<= 1) {
        for (int j = kk >> 1; j > 0; j >>= 1) {
            for (int i = threadIdx.x; i < n; i += blockDim.x) {
                int ixj = i ^ j;
                if (ixj > i) {
                    bool dir = ((i & kk) == 0);
                    float a = key[i], b = key[ixj];
                    if ((a < b) == dir) {
                        key[i] = b; key[ixj] = a;
                        int tmp = kid[i]; kid[i] = kid[ixj]; kid[ixj] = tmp;
                    }
                }
            }
            __syncthreads();
        }
    }
    for (int i = threadIdx.x; i < n; i += blockDim.x) {
        int old = g * n + kid[i];
        if (i < k) {
            int nid = g * k + i;
            newpos[old] = nid;
            sel[nid]    = old;
            scale[nid]  = tanhf(key[i]);
        } else {
            newpos[old] = -1;
        }
    }
}

// ----------------------------------------------------------------------------
// pooled[new] = hrelu[sel[new]] * scale[new]   (one wave per new node)
__global__ __launch_bounds__(256) void pool_gather_kernel(const float* __restrict__ hrelu,
                                                          const int* __restrict__ sel,
                                                          const float* __restrict__ scale,
                                                          float* __restrict__ pooled, int nnew) {
    int wid  = (blockIdx.x * blockDim.x + threadIdx.x) >> 6;
    int lane = threadIdx.x & 63;
    if (wid >= nnew) return;
    int old  = sel[wid];
    float sc = scale[wid];
    float2 v = ((const float2*)hrelu)[(long long)old * 64 + lane];
    float2 o; o.x = v.x * sc; o.y = v.y * sc;
    ((float2*)pooled)[(long long)wid * 64 + lane] = o;
}

// ----------------------------------------------------------------------------
// two-phase readout.
__global__ __launch_bounds__(128) void readout_part_kernel(const float* __restrict__ h,
                                                           float* __restrict__ part, int npg) {
    int b = blockIdx.x;
    int g = b >> 3, c = b & 7;
    int f = threadIdx.x;
    int chunk = npg >> 3;
    const float* base = h + ((long long)g * npg + (long long)c * chunk) * 128;
    float m = -INFINITY, s = 0.f;
    for (int n = 0; n < chunk; ++n) {
        float v = base[n * 128 + f];
        m = fmaxf(m, v);
        s += v;
    }
    part[(size_t)b * 256 + f]       = m;
    part[(size_t)b * 256 + 128 + f] = s;
}

__global__ __launch_bounds__(128) void readout_fin_kernel(const float* __restrict__ part,
                                                          float* __restrict__ xout, int npg) {
    int g = blockIdx.x, f = threadIdx.x;
    float m = -INFINITY, s = 0.f;
    #pragma unroll
    for (int c = 0; c < 8; ++c) {
        m = fmaxf(m, part[(size_t)(g * 8 + c) * 256 + f]);
        s += part[(size_t)(g * 8 + c) * 256 + 128 + f];
    }
    xout[g * 256 + f]       = m;
    xout[g * 256 + 128 + f] = s / (float)npg;
}

// ----------------------------------------------------------------------------
// final MLP head + log_softmax. block=(128), grid=(64)
__global__ __launch_bounds__(128) void mlp_kernel(const float* __restrict__ x1,
                                                  const float* __restrict__ x2,
                                                  const float* __restrict__ x3,
                                                  const float* __restrict__ L1w,
                                                  const float* __restrict__ L1b,
                                                  const float* __restrict__ L2w,
                                                  const float* __restrict__ L2b,
                                                  const float* __restrict__ L3w,
                                                  const float* __restrict__ L3b,
                                                  float* __restrict__ out) {
    __shared__ float z[256], z1[128], z2[64], z3[6];
    int g = blockIdx.x, t = threadIdx.x;
    z[t]       = fmaxf(x1[g * 256 + t], 0.f) + fmaxf(x2[g * 256 + t], 0.f) +
                 fmaxf(x3[g * 256 + t], 0.f);
    z[t + 128] = fmaxf(x1[g * 256 + 128 + t], 0.f) + fmaxf(x2[g * 256 + 128 + t], 0.f) +
                 fmaxf(x3[g * 256 + 128 + t], 0.f);
    __syncthreads();
    float a = L1b[t];
    for (int i = 0; i < 256; ++i) a += z[i] * L1w[i * 128 + t];
    z1[t] = fmaxf(a, 0.f);
    __syncthreads();
    if (t < 64) {
        float b = L2b[t];
        for (int i = 0; i < 128; ++i) b += z1[i] * L2w[i * 64 + t];
        z2[t] = fmaxf(b, 0.f);
    }
    __syncthreads();
    if (t < 6) {
        float c = L3b[t];
        for (int i = 0; i < 64; ++i) c += z2[i] * L3w[i * 6 + t];
        z3[t] = c;
    }
    __syncthreads();
    if (t == 0) {
        float m = z3[0];
        for (int i = 1; i < 6; ++i) m = fmaxf(m, z3[i]);
        float s = 0.f;
        for (int i = 0; i < 6; ++i) s += expf(z3[i] - m);
        float ls = m + logf(s);
        for (int i = 0; i < 6; ++i) out[g * 6 + i] = z3[i] - ls;
    }
}

// ----------------------------------------------------------------------------
static inline void run_scan(const int* deg, int* bsum, int* offs, int* cur, float* rs,
                            int n, hipStream_t stream) {
    int nb = n / 1024;
    scan_sum_kernel<<<nb, 256, 0, stream>>>(deg, bsum);
    scan_bsum_kernel<<<1, 64, 0, stream>>>(bsum, nb);
    scan_out_kernel<<<nb, 256, 0, stream>>>(deg, bsum, offs, cur, rs, n);
}

static inline void run_readout(const float* h, float* part, float* xout, int npg,
                               hipStream_t stream) {
    readout_part_kernel<<<NB * 8, 128, 0, stream>>>(h, part, npg);
    readout_fin_kernel<<<NB, 128, 0, stream>>>(part, xout, npg);
}

extern "C" void kernel_launch(void* const* d_in, const int* in_sizes, int n_in,
                              void* d_out, int out_size, void* d_ws, size_t ws_size,
                              hipStream_t stream) {
    const float* x    = (const float*)d_in[0];
    const int*   ei   = (const int*)d_in[1];
    const float* W1   = (const float*)d_in[3];
    const float* b1   = (const float*)d_in[4];
    const float* ws1  = (const float*)d_in[5];
    const float* W2   = (const float*)d_in[6];
    const float* b2   = (const float*)d_in[7];
    const float* ws2  = (const float*)d_in[8];
    const float* W3   = (const float*)d_in[9];
    const float* b3   = (const float*)d_in[10];
    const float* ws3  = (const float*)d_in[11];
    const float* L1w  = (const float*)d_in[12];
    const float* L1b  = (const float*)d_in[13];
    const float* L2w  = (const float*)d_in[14];
    const float* L2b  = (const float*)d_in[15];
    const float* L3w  = (const float*)d_in[16];
    const float* L3b  = (const float*)d_in[17];
    float* out = (float*)d_out;

    // workspace layout (256B aligned regions)
    char* w = (char*)d_ws;
    auto alloc = [&](size_t nbytes) { char* p = w; w += (nbytes + 255) & ~(size_t)255; return p; };
    float* A     = (float*)alloc((size_t)NN1 * 128 * 4);   // h = X @ W
    float* Bf    = (float*)alloc((size_t)NN1 * 128 * 4);   // relu(out); tail hosts csrB
    float* P1    = (float*)alloc((size_t)NN2 * 128 * 4);   // pooled stage1
    float* P2    = (float*)alloc((size_t)NN3 * 128 * 4);   // pooled stage2 / bins union
    int*   csrA  = (int*)alloc((size_t)E_TOT * 4);
    int*   deg   = (int*)alloc((size_t)NN1 * 4);
    int*   offsA = (int*)alloc((size_t)(NN1 + 1) * 4);
    int*   offsB = (int*)alloc((size_t)(NN1 + 1) * 4);
    int*   cur   = (int*)alloc((size_t)NN1 * 4);
    float* rs    = (float*)alloc((size_t)NN1 * 4);
    int*   np1   = (int*)alloc((size_t)NN1 * 4);
    int*   np2   = (int*)alloc((size_t)NN2 * 4);
    int*   sel   = (int*)alloc((size_t)NN2 * 4);
    float* scal  = (float*)alloc((size_t)NN2 * 4);
    float* score = (float*)alloc((size_t)NN1 * 4);
    float* x1    = (float*)alloc((size_t)NB * 256 * 4);
    float* x2    = (float*)alloc((size_t)NB * 256 * 4);
    float* x3    = (float*)alloc((size_t)NB * 256 * 4);
    float* part  = (float*)alloc((size_t)NB * 8 * 256 * 4);
    int*   bsum  = (int*)alloc(256 * 4);
    int*   gcur  = (int*)alloc(64 * 4);
    int*   flag  = (int*)alloc(256);

    // overlays (regions dead at time of use)
    int* bins = (int*)P2;                       // 64*CAP*4 = 4.7MB < NN3*128*4; dead before stage-2 pool
    int* csrB = (int*)(Bf + (size_t)NN2 * 128); // Bf tail unused after stage-1 pool

    probe_kernel<<<1, 64, 0, stream>>>(ei, flag);

    // ---------------- stage 1 (two-level counting-sort CSR build) ----------------
    hipMemsetAsync(gcur, 0, 64 * 4, stream);
    bin_pack_kernel<<<E_TOT / 4096, 256, 0, stream>>>(ei, flag, bins, gcur);
    graph_csr_kernel<<<NB, 1024, 0, stream>>>(bins, gcur, offsA, rs, csrA);
    gemm_tiled_kernel<<<NN1 / 128, 256, 0, stream>>>(x, W1, A);
    agg_kernel<<<NN1 / 4, 256, 0, stream>>>(A, csrA, offsA, rs, b1, ws1, Bf, score, 1024, 8);
    topk_kernel<<<NB, 512, 0, stream>>>(score, np1, sel, scal, 1024, 512);
    pool_gather_kernel<<<NN2 / 4, 256, 0, stream>>>(Bf, sel, scal, P1, NN2);
    run_readout(P1, part, x1, 512, stream);

    // ---------------- stage 2 (CSR from stage-1 CSR) ----------------
    csr_count_kernel<<<NN2 / 4, 256, 0, stream>>>(offsA, csrA, np1, sel, deg, NN2);
    run_scan(deg, bsum, offsB, cur, rs, NN2, stream);
    csr_scatter_kernel<<<NN2 / 4, 256, 0, stream>>>(offsA, csrA, np1, sel, offsB, csrB, NN2);
    gemm_tiled_kernel<<<NN2 / 128, 256, 0, stream>>>(P1, W2, A);
    agg_kernel<<<NN2 / 4, 256, 0, stream>>>(A, csrB, offsB, rs, b2, ws2, Bf, score, 512, 7);
    topk_kernel<<<NB, 512, 0, stream>>>(score, np2, sel, scal, 512, 256);
    pool_gather_kernel<<<NN3 / 4, 256, 0, stream>>>(Bf, sel, scal, P2, NN3);
    run_readout(P2, part, x2, 256, stream);

    // ---------------- stage 3 (CSR from stage-2 CSR) ----------------
    csr_count_kernel<<<NN3 / 4, 256, 0, stream>>>(offsB, csrB, np2, sel, deg, NN3);
    run_scan(deg, bsum, offsA, cur, rs, NN3, stream);
    csr_scatter_kernel<<<NN3 / 4, 256, 0, stream>>>(offsB, csrB, np2, sel, offsA, csrA, NN3);
    gemm_tiled_kernel<<<NN3 / 128, 256, 0, stream>>>(P2, W3, A);
    agg_kernel<<<NN3 / 4, 256, 0, stream>>>(A, csrA, offsA, rs, b3, ws3, Bf, score, 256, 6);
    run_readout(Bf, part, x3, 256, stream);

    // ---------------- head ----------------
    mlp_kernel<<<NB, 128, 0, stream>>>(x1, x2, x3, L1w, L1b, L2w, L2b, L3w, L3b, out);
}